// Round 1
// 916.957 us; speedup vs baseline: 1.1878x; 1.1878x over previous
//
#include <hip/hip_runtime.h>
#include <math.h>

#define NLEV 12
#define TSIZE (1u << 19)
#define TMASK (TSIZE - 1u)
#define DOUT 257
#define PPB 256            // points per block (fused fallback / encode)
#define EMB 24             // L*F feature dim
#define RSTRIDE 28         // fused fallback emb row stride
#define TP 128             // points per tile in head kernel

struct ResArr { float r[NLEV]; };

// =====================================================================
// Phase A: hash-grid encode, one thread per point, no LDS / no barrier.
// Stores emb as SoA float2 planes: emb2[l*N + p]  (coalesced 8B stores).
// Rationale: the gather phase is latency-bound; stripping Phase-B's LDS
// and register footprint lets 6-8 waves/SIMD reside (vs ~3 fused).
// =====================================================================
__global__ __launch_bounds__(256)
void encode_kernel(const float* __restrict__ xin,
                   const float* __restrict__ tables,
                   float2* __restrict__ emb2,
                   int N, ResArr res)
{
    const int p = blockIdx.x * 256 + threadIdx.x;
    if (p >= N) return;
    const float px = xin[3 * p + 0];
    const float py = xin[3 * p + 1];
    const float pz = xin[3 * p + 2];
#pragma unroll 2
    for (int l = 0; l < NLEV; ++l) {
        const float rf = res.r[l];
        const float sx = px * rf, sy = py * rf, sz = pz * rf;
        const float gx = floorf(sx), gy = floorf(sy), gz = floorf(sz);
        const float tx = sx - gx, ty = sy - gy, tz = sz - gz;
        const unsigned ix = (unsigned)gx, iy = (unsigned)gy, iz = (unsigned)gz;
        // primes: {1, 2654435761, 805459861}; uint32 wraparound
        const unsigned hx0 = ix,               hx1 = ix + 1u;
        const unsigned hy0 = iy * 2654435761u, hy1 = hy0 + 2654435761u;
        const unsigned hz0 = iz * 805459861u,  hz1 = hz0 + 805459861u;
        const float2* __restrict__ tab = (const float2*)tables + (size_t)l * TSIZE;
        float2 f0 = tab[(hx0 ^ hy0 ^ hz0) & TMASK];
        float2 f1 = tab[(hx0 ^ hy0 ^ hz1) & TMASK];
        float2 f2 = tab[(hx0 ^ hy1 ^ hz0) & TMASK];
        float2 f3 = tab[(hx0 ^ hy1 ^ hz1) & TMASK];
        float2 f4 = tab[(hx1 ^ hy0 ^ hz0) & TMASK];
        float2 f5 = tab[(hx1 ^ hy0 ^ hz1) & TMASK];
        float2 f6 = tab[(hx1 ^ hy1 ^ hz0) & TMASK];
        float2 f7 = tab[(hx1 ^ hy1 ^ hz1) & TMASK];
        const float u0 = 1.0f - tx, u1 = tx;
        const float v0 = 1.0f - ty, v1 = ty;
        const float s0 = 1.0f - tz, s1 = tz;
        const float w0 = (u0 * v0) * s0;
        const float w1 = (u0 * v0) * s1;
        const float w2 = (u0 * v1) * s0;
        const float w3 = (u0 * v1) * s1;
        const float w4 = (u1 * v0) * s0;
        const float w5 = (u1 * v0) * s1;
        const float w6 = (u1 * v1) * s0;
        const float w7 = (u1 * v1) * s1;
        float a = w0 * f0.x;
        float b = w0 * f0.y;
        a = fmaf(w1, f1.x, a);  b = fmaf(w1, f1.y, b);
        a = fmaf(w2, f2.x, a);  b = fmaf(w2, f2.y, b);
        a = fmaf(w3, f3.x, a);  b = fmaf(w3, f3.y, b);
        a = fmaf(w4, f4.x, a);  b = fmaf(w4, f4.y, b);
        a = fmaf(w5, f5.x, a);  b = fmaf(w5, f5.y, b);
        a = fmaf(w6, f6.x, a);  b = fmaf(w6, f6.y, b);
        a = fmaf(w7, f7.x, a);  b = fmaf(w7, f7.y, b);
        emb2[(size_t)l * N + p] = make_float2(a, b);
    }
}

// =====================================================================
// Phase B: head GEMV, pure streaming. 12 KB LDS tile (TP=128 points),
// broadcast-only LDS reads (conflict-free), thread j owns column j.
// Column 256 handled as a 128-thread tail with uniform (s_load) W reads
// -> no wext[24] register array. ~40 VGPR + 12 KB LDS -> 32 waves/CU.
// =====================================================================
__global__ __launch_bounds__(256)
void head_kernel(const float2* __restrict__ emb2,
                 const float* __restrict__ Wm,
                 const float* __restrict__ bias,
                 float* __restrict__ out,
                 int N)
{
    __shared__ float2 sm[NLEV][TP];       // 12288 B
    const int tid  = threadIdx.x;
    const int base = blockIdx.x * TP;
    const int nv   = min(TP, N - base);

    // W column for j = tid (coalesced: lane t reads W[k*257 + t])
    float wcol[EMB];
#pragma unroll
    for (int k = 0; k < EMB; ++k) wcol[k] = Wm[k * DOUT + tid];
    const float bj = bias[tid];

    // stage emb tile: 1536 float2, 256 threads -> 6 coalesced iters
#pragma unroll
    for (int i = 0; i < (NLEV * TP) / 256; ++i) {
        const int f = i * 256 + tid;
        const int l = f >> 7;             // TP == 128
        const int n = f & (TP - 1);
        if (n < nv) sm[l][n] = emb2[(size_t)l * N + base + n];
    }
    __syncthreads();

    float* orow = out + (size_t)base * DOUT + tid;
    for (int n = 0; n < nv; ++n, orow += DOUT) {
        float accA = bj, accB = 0.0f;     // 2 chains for FMA-latency ILP
#pragma unroll
        for (int l = 0; l < NLEV; l += 2) {
            const float2 q0 = sm[l][n];
            const float2 q1 = sm[l + 1][n];
            accA = fmaf(q0.x, wcol[2 * l + 0], accA);
            accB = fmaf(q0.y, wcol[2 * l + 1], accB);
            accA = fmaf(q1.x, wcol[2 * l + 2], accA);
            accB = fmaf(q1.y, wcol[2 * l + 3], accB);
        }
        *orow = accA + accB;
    }

    // column 256 for this tile: first nv threads, one point each.
    // Wm reads are wave-uniform -> scalar cache; stores land in lines
    // just written by the main loop -> merged in L2.
    if (tid < nv) {
        float acc = bias[256];
#pragma unroll
        for (int l = 0; l < NLEV; ++l) {
            const float2 q = sm[l][tid];
            acc = fmaf(q.x, Wm[(2 * l) * DOUT + 256],
                  fmaf(q.y, Wm[(2 * l + 1) * DOUT + 256], acc));
        }
        out[(size_t)(base + tid) * DOUT + 256] = acc;
    }
}

// =====================================================================
// Fallback: original fused kernel (known-good, 637 us/dispatch), used
// only if the workspace cannot hold the 50.3 MB emb intermediate.
// =====================================================================
__global__ __launch_bounds__(256)
void hashgrid_head_kernel(const float* __restrict__ xin,
                          const float* __restrict__ tables,
                          const float* __restrict__ Wm,
                          const float* __restrict__ bias,
                          float* __restrict__ out,
                          int N, ResArr res)
{
    __shared__ float emb[PPB * RSTRIDE];
    const int tid  = threadIdx.x;
    const int base = blockIdx.x * PPB;
    const int p    = base + tid;

    float wcol[EMB];
#pragma unroll
    for (int k = 0; k < EMB; ++k) wcol[k] = Wm[k * DOUT + tid];
    const float bj = bias[tid];

    const bool extra = (tid < 64);
    float wext[EMB];
    float bext = 0.0f;
    if (extra) {
#pragma unroll
        for (int k = 0; k < EMB; ++k) wext[k] = Wm[k * DOUT + 256];
        bext = bias[256];
    }

    if (p < N) {
        const float px = xin[3 * p + 0];
        const float py = xin[3 * p + 1];
        const float pz = xin[3 * p + 2];
#pragma unroll 2
        for (int l = 0; l < NLEV; ++l) {
            const float rf = res.r[l];
            const float sx = px * rf, sy = py * rf, sz = pz * rf;
            const float gx = floorf(sx), gy = floorf(sy), gz = floorf(sz);
            const float tx = sx - gx, ty = sy - gy, tz = sz - gz;
            const unsigned ix = (unsigned)gx, iy = (unsigned)gy, iz = (unsigned)gz;
            const unsigned hx0 = ix,               hx1 = ix + 1u;
            const unsigned hy0 = iy * 2654435761u, hy1 = hy0 + 2654435761u;
            const unsigned hz0 = iz * 805459861u,  hz1 = hz0 + 805459861u;
            const float2* __restrict__ tab = (const float2*)tables + (size_t)l * TSIZE;
            float2 f0 = tab[(hx0 ^ hy0 ^ hz0) & TMASK];
            float2 f1 = tab[(hx0 ^ hy0 ^ hz1) & TMASK];
            float2 f2 = tab[(hx0 ^ hy1 ^ hz0) & TMASK];
            float2 f3 = tab[(hx0 ^ hy1 ^ hz1) & TMASK];
            float2 f4 = tab[(hx1 ^ hy0 ^ hz0) & TMASK];
            float2 f5 = tab[(hx1 ^ hy0 ^ hz1) & TMASK];
            float2 f6 = tab[(hx1 ^ hy1 ^ hz0) & TMASK];
            float2 f7 = tab[(hx1 ^ hy1 ^ hz1) & TMASK];
            const float u0 = 1.0f - tx, u1 = tx;
            const float v0 = 1.0f - ty, v1 = ty;
            const float s0 = 1.0f - tz, s1 = tz;
            const float w0 = (u0 * v0) * s0;
            const float w1 = (u0 * v0) * s1;
            const float w2 = (u0 * v1) * s0;
            const float w3 = (u0 * v1) * s1;
            const float w4 = (u1 * v0) * s0;
            const float w5 = (u1 * v0) * s1;
            const float w6 = (u1 * v1) * s0;
            const float w7 = (u1 * v1) * s1;
            float a = w0 * f0.x;
            float b = w0 * f0.y;
            a = fmaf(w1, f1.x, a);  b = fmaf(w1, f1.y, b);
            a = fmaf(w2, f2.x, a);  b = fmaf(w2, f2.y, b);
            a = fmaf(w3, f3.x, a);  b = fmaf(w3, f3.y, b);
            a = fmaf(w4, f4.x, a);  b = fmaf(w4, f4.y, b);
            a = fmaf(w5, f5.x, a);  b = fmaf(w5, f5.y, b);
            a = fmaf(w6, f6.x, a);  b = fmaf(w6, f6.y, b);
            a = fmaf(w7, f7.x, a);  b = fmaf(w7, f7.y, b);
            *(float2*)&emb[tid * RSTRIDE + 2 * l] = make_float2(a, b);
        }
    }

    __syncthreads();

    const int nvalid = min(PPB, N - base);
    for (int n = 0; n < nvalid; ++n) {
        const float4* e4 = (const float4*)&emb[n * RSTRIDE];
        float4 q0 = e4[0], q1 = e4[1], q2 = e4[2], q3 = e4[3], q4 = e4[4], q5 = e4[5];
        float e[EMB] = {q0.x, q0.y, q0.z, q0.w, q1.x, q1.y, q1.z, q1.w,
                        q2.x, q2.y, q2.z, q2.w, q3.x, q3.y, q3.z, q3.w,
                        q4.x, q4.y, q4.z, q4.w, q5.x, q5.y, q5.z, q5.w};
        float acc = bj;
#pragma unroll
        for (int k = 0; k < EMB; ++k) acc = fmaf(e[k], wcol[k], acc);
        out[(size_t)(base + n) * DOUT + tid] = acc;
        if (extra) {
            float acc2 = bext;
#pragma unroll
            for (int k = 0; k < EMB; ++k) acc2 = fmaf(e[k], wext[k], acc2);
            if (tid == 0) out[(size_t)(base + n) * DOUT + 256] = acc2;
        }
    }
}

extern "C" void kernel_launch(void* const* d_in, const int* in_sizes, int n_in,
                              void* d_out, int out_size, void* d_ws, size_t ws_size,
                              hipStream_t stream) {
    const float* xin    = (const float*)d_in[0];
    const float* tables = (const float*)d_in[1];
    const float* Wm     = (const float*)d_in[2];
    const float* bias   = (const float*)d_in[3];
    float* out = (float*)d_out;
    const int N = in_sizes[0] / 3;

    // Replicate numpy: RES = floor(BASE_RES * growth**arange(L)).
    ResArr res;
    const double growth = exp((log(2048.0) - log(16.0)) / 11.0);
    for (int l = 0; l < NLEV; ++l)
        res.r[l] = (float)floor(16.0 * pow(growth, (double)l));

    const size_t need = (size_t)NLEV * (size_t)N * sizeof(float2);
    if (d_ws != nullptr && ws_size >= need) {
        float2* emb2 = (float2*)d_ws;
        hipLaunchKernelGGL(encode_kernel, dim3((N + 255) / 256), dim3(256), 0, stream,
                           xin, tables, emb2, N, res);
        hipLaunchKernelGGL(head_kernel, dim3((N + TP - 1) / TP), dim3(256), 0, stream,
                           emb2, Wm, bias, out, N);
    } else {
        const int grid = (N + PPB - 1) / PPB;
        hipLaunchKernelGGL(hashgrid_head_kernel, dim3(grid), dim3(PPB), 0, stream,
                           xin, tables, Wm, bias, out, N, res);
    }
}